// Round 5
// baseline (130.918 us; speedup 1.0000x reference)
//
#include <hip/hip_runtime.h>
#include <math.h>

typedef unsigned short u16;
typedef unsigned long long u64;
typedef float    f32x4  __attribute__((ext_vector_type(4)));
typedef __bf16   bf16x8 __attribute__((ext_vector_type(8)));

#define NS    32768
#define KC    1024
#define INV_T 100.0f
#define TAU   2.0f

// ws layout (float offsets)
#define C2_OFF   0
#define SUMM_OFF 1024                      // [n][16 halfblocks] float4
#define SUMM_SZ  (NS * 16 * 4)
#define HIST_OFF (SUMM_OFF + SUMM_SZ)
#define PD_OFF   (HIST_OFF + KC)
#define PS_OFF   (PD_OFF + 8192)

// ct: tiled bf16 codebook, 16 tiles (64 codes) x 2048 chunks x 16B = 512 KB
// (lives in d_out, overwritten by refine's quantized output afterwards).
// chunk c within tile = ks*256 + sub*64 + row  (sub = k-octet, row = code 0..63)
#define TILE_U16 16384

__device__ __forceinline__ void gload_lds16(const void* g, void* l) {
    __builtin_amdgcn_global_load_lds((const __attribute__((address_space(1))) void*)g,
                                     (__attribute__((address_space(3))) void*)l, 16, 0, 0);
}

// --------------- cb prep: exact c2 + tiled bf16 codebook (64 blocks) ----
__global__ __launch_bounds__(256) void vq_cbprep(const float* __restrict__ cb,
                                                 u16* __restrict__ ct,
                                                 float* __restrict__ c2) {
    const int b = blockIdx.x;        // 64 blocks: tile T = b>>2, part p = b&3
    const int T = b >> 2, p = b & 3;
    const int t = threadIdx.x, w = t >> 6, lane = t & 63;

    // c2 for 16 rows (exact fp32)
    #pragma unroll
    for (int i = 0; i < 4; ++i) {
        int g = T * 64 + p * 16 + i * 4 + w;
        float4 v = reinterpret_cast<const float4*>(cb)[(size_t)g * 64 + lane];
        float s = v.x * v.x + v.y * v.y + v.z * v.z + v.w * v.w;
        #pragma unroll
        for (int off = 32; off; off >>= 1) s += __shfl_xor(s, off);
        if (lane == 0) c2[g] = s;
    }

    // tiled bf16: this block covers chunks [p*512, p*512+512) of tile T
    #pragma unroll
    for (int i = 0; i < 2; ++i) {
        int c = p * 512 + i * 256 + t;
        int ks = c >> 8, sub = (c >> 6) & 3, row = c & 63;
        const float* src = cb + (size_t)(T * 64 + row) * 256 + ks * 32 + sub * 8;
        float4 a0 = *reinterpret_cast<const float4*>(src);
        float4 a1 = *reinterpret_cast<const float4*>(src + 4);
        bf16x8 v;
        v[0]=(__bf16)a0.x; v[1]=(__bf16)a0.y; v[2]=(__bf16)a0.z; v[3]=(__bf16)a0.w;
        v[4]=(__bf16)a1.x; v[5]=(__bf16)a1.y; v[6]=(__bf16)a1.z; v[7]=(__bf16)a1.w;
        *reinterpret_cast<bf16x8*>(ct + (size_t)T * TILE_U16 + (size_t)c * 8) = v;
    }
}

// ---- distance MFMA: 32KB LDS B, fp32 A register-prefetched, no K barriers ----
// grid 2048 = 128 sample-tiles (256 samples) x 16 code-tiles (64 codes).
// 4 waves; each wave: 64 samples x 64 codes (acc[4][4]).
__global__ __launch_bounds__(256, 3) void vq_dist(const float* __restrict__ x,
                                                  const u16* __restrict__ ct,
                                                  const float* __restrict__ c2,
                                                  float4* __restrict__ summ) {
    __shared__ __align__(16) u16 Bs[TILE_U16];   // 32 KB

    // XCD swizzle: xcd owns 16 consecutive sample-tiles; code-tile minor.
    const int id = blockIdx.x;
    const int xcd = id & 7, r0 = id >> 3;        // r0 0..255
    const int by = xcd * 16 + (r0 >> 4);         // 0..127
    const int bx = r0 & 15;                      // 0..15
    const int sBase = by * 256, cBase = bx * 64;

    const int t = threadIdx.x, w = t >> 6, lane = t & 63;
    const int lo16 = lane & 15, hi = lane >> 4;

    // stage whole 64-code B tile once
    const u16* bT = ct + (size_t)bx * TILE_U16;
    #pragma unroll
    for (int i = 0; i < 8; ++i) {
        int c0 = (i * 4 + w) * 64;
        gload_lds16(bT + (size_t)(c0 + lane) * 8, &Bs[c0 * 8]);
    }
    __syncthreads();

    const float* aw = x + (size_t)(sBase + w * 64) * 256;
    f32x4 acc[4][4];
    #pragma unroll
    for (int m = 0; m < 4; ++m)
        #pragma unroll
        for (int n = 0; n < 4; ++n) acc[m][n] = (f32x4)0.f;

    float4 pa[4][2];
    #define LOADA(ks)                                                              \
        do {                                                                       \
            _Pragma("unroll")                                                      \
            for (int m_ = 0; m_ < 4; ++m_) {                                       \
                const float* ap = aw + (size_t)(m_ * 16 + lo16) * 256 + (ks) * 32 + hi * 8; \
                pa[m_][0] = *reinterpret_cast<const float4*>(ap);                  \
                pa[m_][1] = *reinterpret_cast<const float4*>(ap + 4);              \
            }                                                                      \
        } while (0)

    LOADA(0);
    #pragma unroll
    for (int ks = 0; ks < 8; ++ks) {
        bf16x8 af[4];
        #pragma unroll
        for (int m = 0; m < 4; ++m) {
            bf16x8 v;
            v[0]=(__bf16)pa[m][0].x; v[1]=(__bf16)pa[m][0].y;
            v[2]=(__bf16)pa[m][0].z; v[3]=(__bf16)pa[m][0].w;
            v[4]=(__bf16)pa[m][1].x; v[5]=(__bf16)pa[m][1].y;
            v[6]=(__bf16)pa[m][1].z; v[7]=(__bf16)pa[m][1].w;
            af[m] = v;
        }
        if (ks < 7) LOADA(ks + 1);       // prefetch next K-slice during MFMAs
        bf16x8 bfr[4];
        #pragma unroll
        for (int n = 0; n < 4; ++n)
            bfr[n] = *reinterpret_cast<const bf16x8*>(
                &Bs[((size_t)ks * 256 + hi * 64 + n * 16 + lo16) * 8]);
        #pragma unroll
        for (int m = 0; m < 4; ++m)
            #pragma unroll
            for (int n = 0; n < 4; ++n)
                acc[m][n] = __builtin_amdgcn_mfma_f32_16x16x32_bf16(af[m], bfr[n], acc[m][n], 0, 0, 0);
    }
    #undef LOADA

    // Epilogue: dd = c2 - 2*acc (x^2 cancels in row-internal comparisons)
    float c2v[4];
    #pragma unroll
    for (int j = 0; j < 4; ++j) c2v[j] = c2[cBase + j * 16 + lo16];

    #pragma unroll
    for (int m = 0; m < 4; ++m) {
        #pragma unroll
        for (int r = 0; r < 4; ++r) {
            const int R = sBase + w * 64 + m * 16 + hi * 4 + r;
            float dd[4];
            #pragma unroll
            for (int j = 0; j < 4; ++j) dd[j] = fmaf(-2.0f, acc[m][j][r], c2v[j]);
            float bm = fminf(fminf(dd[0], dd[1]), fminf(dd[2], dd[3]));
            #pragma unroll
            for (int off = 1; off < 16; off <<= 1) bm = fminf(bm, __shfl_xor(bm, off));
            const float thr = bm + TAU;
            u64 mk = 0ull;
            #pragma unroll
            for (int n = 0; n < 4; ++n) {
                u64 b = __ballot(dd[n] < thr);
                mk |= ((b >> (hi * 16)) & 0xFFFFull) << (n * 16);
            }
            if (lo16 == 0) {
                float4 o;
                o.x = bm;
                o.y = 0.f;
                o.z = __uint_as_float((unsigned)(mk & 0xFFFFFFFFull));
                o.w = __uint_as_float((unsigned)(mk >> 32));
                summ[(size_t)R * 16 + bx] = o;
            }
        }
    }
}

// ---------- exact fp32 refine, single-pass, fused gather + histogram ----
__global__ __launch_bounds__(256) void vq_refine(const float* __restrict__ x,
                                                 const float* __restrict__ cb,
                                                 const float* __restrict__ c2,
                                                 const float4* __restrict__ summ,
                                                 float* __restrict__ hist,
                                                 float* __restrict__ pd,
                                                 float* __restrict__ ps,
                                                 float* __restrict__ outq,
                                                 float* __restrict__ out_idx_f) {
    __shared__ int   cd_k[4][128];
    __shared__ float cd_d[4][128];
    __shared__ float rd[4], rs[4];

    const int wid = threadIdx.x >> 6, lane = threadIdx.x & 63;
    const int s = blockIdx.x * 4 + wid;
    const float4 xv = reinterpret_cast<const float4*>(x)[(size_t)s * 64 + lane];

    // exact ||x_s||^2 (all lanes)
    float x2s = xv.x * xv.x + xv.y * xv.y + xv.z * xv.z + xv.w * xv.w;
    #pragma unroll
    for (int off = 32; off; off >>= 1) x2s += __shfl_xor(x2s, off);

    // parallel min over the 16 half-block summaries
    float gm = summ[(size_t)s * 16 + (lane & 15)].x;
    #pragma unroll
    for (int off = 1; off < 16; off <<= 1) gm = fminf(gm, __shfl_xor(gm, off));
    const float lim = gm + TAU;

    float m = 3.4e38f, S1 = 0.f, S2 = 0.f;
    int bk = 0, cnt = 0;
    for (int hb = 0; hb < 16; ++hb) {
        float4 sm = summ[(size_t)s * 16 + hb];
        if (sm.x > lim) continue;
        u64 mk = ((u64)__float_as_uint(sm.w) << 32) | __float_as_uint(sm.z);
        while (mk) {
            int b = __ffsll(mk) - 1; mk &= mk - 1;
            int k = hb * 64 + b;
            float4 cv = reinterpret_cast<const float4*>(cb)[(size_t)k * 64 + lane];
            float r = xv.x * cv.x + xv.y * cv.y + xv.z * cv.z + xv.w * cv.w;
            #pragma unroll
            for (int off = 32; off; off >>= 1) r += __shfl_xor(r, off);
            float dk = (x2s - 2.0f * r) + c2[k];
            if (lane == 0 && cnt < 128) { cd_k[wid][cnt] = k; cd_d[wid][cnt] = dk; }
            ++cnt;
            if (S1 == 0.f)    { m = dk; S1 = 1.f; S2 = 0.f; bk = k; }
            else if (dk < m)  { float f = __expf((dk - m) * INV_T);
                                S2 = f * (S2 + (m - dk) * S1);
                                S1 = S1 * f + 1.f; m = dk; bk = k; }
            else              { float e = __expf((m - dk) * INV_T);
                                S1 += e; S2 += e * (dk - m); }
        }
    }
    float sent = S2 * INV_T / S1 + logf(S1);
    if (lane == 0) { rd[wid] = m; rs[wid] = sent; }
    __syncthreads();

    // lane-parallel histogram update
    if (cnt > 128) cnt = 128;
    for (int c = lane; c < cnt; c += 64) {
        float dk = cd_d[wid][c]; int k = cd_k[wid][c];
        atomicAdd(&hist[k], __expf((m - dk) * INV_T) / S1);
    }

    // fused gather: quantized row = codebook[bk]
    reinterpret_cast<float4*>(outq)[(size_t)s * 64 + lane] =
        reinterpret_cast<const float4*>(cb)[(size_t)bk * 64 + lane];
    if (lane == 0) out_idx_f[s] = (float)bk;

    if (threadIdx.x == 0) {
        pd[blockIdx.x] = rd[0] + rd[1] + rd[2] + rd[3];
        ps[blockIdx.x] = rs[0] + rs[1] + rs[2] + rs[3];
    }
}

// -------------------------------------------------------------- finalize ----
__global__ __launch_bounds__(256) void vq_finalize(const float* __restrict__ hist,
                                                   const float* __restrict__ pd,
                                                   const float* __restrict__ ps,
                                                   float* __restrict__ loss_out) {
    float ae = 0.f, sd = 0.f, se = 0.f;
    for (int k = threadIdx.x; k < KC; k += 256) {
        float p = hist[k] * (1.0f / (float)NS);
        ae += -p * logf(p + 1e-5f);
    }
    for (int b = threadIdx.x; b < 8192; b += 256) { sd += pd[b]; se += ps[b]; }
    #pragma unroll
    for (int off = 32; off; off >>= 1) {
        ae += __shfl_xor(ae, off); sd += __shfl_xor(sd, off); se += __shfl_xor(se, off);
    }
    __shared__ float r[3][4];
    int wid = threadIdx.x >> 6, lane = threadIdx.x & 63;
    if (lane == 0) { r[0][wid] = ae; r[1][wid] = sd; r[2][wid] = se; }
    __syncthreads();
    if (threadIdx.x == 0) {
        float AE = r[0][0] + r[0][1] + r[0][2] + r[0][3];
        float SD = r[1][0] + r[1][1] + r[1][2] + r[1][3];
        float SE = r[2][0] + r[2][1] + r[2][2] + r[2][3];
        float latent = 1.25f * SD / 8388608.0f;
        loss_out[0] = latent + 0.1f * (SE * (1.0f / (float)NS) - AE);
    }
}

extern "C" void kernel_launch(void* const* d_in, const int* in_sizes, int n_in,
                              void* d_out, int out_size, void* d_ws, size_t ws_size,
                              hipStream_t stream) {
    const float* x  = (const float*)d_in[0];
    const float* cb = (const float*)d_in[1];
    float* out = (float*)d_out;
    float* ws  = (float*)d_ws;

    // tiled bf16 codebook in first 512 KB of d_out (overwritten by refine later)
    u16* ct = (u16*)d_out;

    hipMemsetAsync(ws + HIST_OFF, 0, KC * sizeof(float), stream);

    vq_cbprep<<<64, 256, 0, stream>>>(cb, ct, ws + C2_OFF);
    vq_dist<<<2048, 256, 0, stream>>>(x, ct, ws + C2_OFF, (float4*)(ws + SUMM_OFF));
    vq_refine<<<NS / 4, 256, 0, stream>>>(x, cb, ws + C2_OFF,
                                          (const float4*)(ws + SUMM_OFF),
                                          ws + HIST_OFF, ws + PD_OFF, ws + PS_OFF,
                                          out, out + 8388609);
    vq_finalize<<<1, 256, 0, stream>>>(ws + HIST_OFF, ws + PD_OFF, ws + PS_OFF,
                                       out + 8388608);
}

// Round 6
// 106.737 us; speedup vs baseline: 1.2265x; 1.2265x over previous
//
#include <hip/hip_runtime.h>
#include <math.h>

typedef unsigned short u16;
typedef unsigned long long u64;
typedef float    f32x4  __attribute__((ext_vector_type(4)));
typedef __bf16   bf16x8 __attribute__((ext_vector_type(8)));

#define NS    32768
#define KC    1024
#define INV_T 100.0f
#define TAU   2.0f

// ws layout (float offsets)
#define C2_OFF   0
#define SUMM_OFF 1024                      // [n][16 halfblocks] float4
#define SUMM_SZ  (NS * 16 * 4)
#define HIST_OFF (SUMM_OFF + SUMM_SZ)
#define PD_OFF   (HIST_OFF + KC)
#define PS_OFF   (PD_OFF + 8192)

// ct: tiled bf16 codebook, 16 tiles (64 codes) x 2048 chunks x 16B = 512 KB
// (lives in d_out, overwritten by refine's quantized output afterwards).
// chunk c within tile = ks*256 + sub*64 + row  (sub = k-octet, row = code 0..63)
#define TILE_U16 16384

__device__ __forceinline__ void gload_lds16(const void* g, void* l) {
    __builtin_amdgcn_global_load_lds((const __attribute__((address_space(1))) void*)g,
                                     (__attribute__((address_space(3))) void*)l, 16, 0, 0);
}

// --------------- cb prep: exact c2 + tiled bf16 codebook (64 blocks) ----
__global__ __launch_bounds__(256) void vq_cbprep(const float* __restrict__ cb,
                                                 u16* __restrict__ ct,
                                                 float* __restrict__ c2) {
    const int b = blockIdx.x;        // 64 blocks: tile T = b>>2, part p = b&3
    const int T = b >> 2, p = b & 3;
    const int t = threadIdx.x, w = t >> 6, lane = t & 63;

    // c2 for 16 rows (exact fp32)
    #pragma unroll
    for (int i = 0; i < 4; ++i) {
        int g = T * 64 + p * 16 + i * 4 + w;
        float4 v = reinterpret_cast<const float4*>(cb)[(size_t)g * 64 + lane];
        float s = v.x * v.x + v.y * v.y + v.z * v.z + v.w * v.w;
        #pragma unroll
        for (int off = 32; off; off >>= 1) s += __shfl_xor(s, off);
        if (lane == 0) c2[g] = s;
    }

    // tiled bf16: this block covers chunks [p*512, p*512+512) of tile T
    #pragma unroll
    for (int i = 0; i < 2; ++i) {
        int c = p * 512 + i * 256 + t;
        int ks = c >> 8, sub = (c >> 6) & 3, row = c & 63;
        const float* src = cb + (size_t)(T * 64 + row) * 256 + ks * 32 + sub * 8;
        float4 a0 = *reinterpret_cast<const float4*>(src);
        float4 a1 = *reinterpret_cast<const float4*>(src + 4);
        bf16x8 v;
        v[0]=(__bf16)a0.x; v[1]=(__bf16)a0.y; v[2]=(__bf16)a0.z; v[3]=(__bf16)a0.w;
        v[4]=(__bf16)a1.x; v[5]=(__bf16)a1.y; v[6]=(__bf16)a1.z; v[7]=(__bf16)a1.w;
        *reinterpret_cast<bf16x8*>(ct + (size_t)T * TILE_U16 + (size_t)c * 8) = v;
    }
}

// ---- distance MFMA: A persistent in registers, B dbuf-streamed via LDS ----
// grid 512 = 128 sample-groups (256 samples) x 4 code-quarters (256 codes).
// 4 waves; each wave holds A for 64 samples x 256 k in 128 VGPRs, loops over
// 4 code-tiles of 64 codes with STAGE(next)-before-compute pipelining.
__global__ __launch_bounds__(256, 2) void vq_dist(const float* __restrict__ x,
                                                  const u16* __restrict__ ct,
                                                  const float* __restrict__ c2,
                                                  float4* __restrict__ summ) {
    __shared__ __align__(16) u16 Bs[2][TILE_U16];   // 2 x 32 KB

    // XCD swizzle: each XCD owns 16 sample-groups x 4 code-quarters
    const int id = blockIdx.x;
    const int xcd = id & 7, r0 = id >> 3;          // r0 0..63
    const int sq = xcd * 16 + (r0 >> 2);           // 0..127
    const int cq = r0 & 3;                         // 0..3
    const int sBase = sq * 256;
    const int tile0 = cq * 4;

    const int t = threadIdx.x, w = t >> 6, lane = t & 63;
    const int lo16 = lane & 15, hi = lane >> 4;

    #define STAGE(buf, tile)                                                      \
        do {                                                                      \
            const u16* bT_ = ct + (size_t)(tile) * TILE_U16;                      \
            _Pragma("unroll")                                                     \
            for (int i_ = 0; i_ < 8; ++i_) {                                      \
                int c0_ = w * 512 + i_ * 64;                                      \
                gload_lds16(bT_ + (size_t)(c0_ + lane) * 8, &Bs[buf][c0_ * 8]);   \
            }                                                                     \
        } while (0)

    STAGE(0, tile0);

    // Load this wave's entire A-operand into registers (once), fp32 -> bf16.
    const float* aw = x + (size_t)(sBase + w * 64) * 256;
    bf16x8 af[4][8];
    #pragma unroll
    for (int m = 0; m < 4; ++m) {
        #pragma unroll
        for (int ks = 0; ks < 8; ++ks) {
            const float* ap = aw + (size_t)(m * 16 + lo16) * 256 + ks * 32 + hi * 8;
            float4 a0 = *reinterpret_cast<const float4*>(ap);
            float4 a1 = *reinterpret_cast<const float4*>(ap + 4);
            bf16x8 v;
            v[0]=(__bf16)a0.x; v[1]=(__bf16)a0.y; v[2]=(__bf16)a0.z; v[3]=(__bf16)a0.w;
            v[4]=(__bf16)a1.x; v[5]=(__bf16)a1.y; v[6]=(__bf16)a1.z; v[7]=(__bf16)a1.w;
            af[m][ks] = v;
        }
    }
    __syncthreads();

    int cur = 0;
    for (int tt = 0; tt < 4; ++tt) {
        if (tt < 3) STAGE(cur ^ 1, tile0 + tt + 1);   // overlaps with MFMAs below

        const u16* bsc = &Bs[cur][0];
        f32x4 acc[4][4];
        #pragma unroll
        for (int m = 0; m < 4; ++m)
            #pragma unroll
            for (int n = 0; n < 4; ++n) acc[m][n] = (f32x4)0.f;

        #pragma unroll
        for (int ks = 0; ks < 8; ++ks) {
            bf16x8 bfr[4];
            #pragma unroll
            for (int n = 0; n < 4; ++n)
                bfr[n] = *reinterpret_cast<const bf16x8*>(
                    &bsc[((size_t)ks * 256 + hi * 64 + n * 16 + lo16) * 8]);
            #pragma unroll
            for (int m = 0; m < 4; ++m)
                #pragma unroll
                for (int n = 0; n < 4; ++n)
                    acc[m][n] = __builtin_amdgcn_mfma_f32_16x16x32_bf16(af[m][ks], bfr[n], acc[m][n], 0, 0, 0);
        }

        // Epilogue for this 64-code tile: dd = c2 - 2*acc (x^2 cancels)
        const int cBase = (tile0 + tt) * 64;
        float c2v[4];
        #pragma unroll
        for (int j = 0; j < 4; ++j) c2v[j] = c2[cBase + j * 16 + lo16];

        #pragma unroll
        for (int m = 0; m < 4; ++m) {
            #pragma unroll
            for (int r = 0; r < 4; ++r) {
                const int R = sBase + w * 64 + m * 16 + hi * 4 + r;
                float dd[4];
                #pragma unroll
                for (int j = 0; j < 4; ++j) dd[j] = fmaf(-2.0f, acc[m][j][r], c2v[j]);
                float bm = fminf(fminf(dd[0], dd[1]), fminf(dd[2], dd[3]));
                #pragma unroll
                for (int off = 1; off < 16; off <<= 1) bm = fminf(bm, __shfl_xor(bm, off));
                const float thr = bm + TAU;
                u64 mk = 0ull;
                #pragma unroll
                for (int n = 0; n < 4; ++n) {
                    u64 b = __ballot(dd[n] < thr);
                    mk |= ((b >> (hi * 16)) & 0xFFFFull) << (n * 16);
                }
                if (lo16 == 0) {
                    float4 o;
                    o.x = bm;
                    o.y = 0.f;
                    o.z = __uint_as_float((unsigned)(mk & 0xFFFFFFFFull));
                    o.w = __uint_as_float((unsigned)(mk >> 32));
                    summ[(size_t)R * 16 + tile0 + tt] = o;
                }
            }
        }
        __syncthreads();     // stage(next) complete; buffer swap safe
        cur ^= 1;
    }
    #undef STAGE
}

// ---------- exact fp32 refine, single-pass, fused gather + histogram ----
__global__ __launch_bounds__(256) void vq_refine(const float* __restrict__ x,
                                                 const float* __restrict__ cb,
                                                 const float* __restrict__ c2,
                                                 const float4* __restrict__ summ,
                                                 float* __restrict__ hist,
                                                 float* __restrict__ pd,
                                                 float* __restrict__ ps,
                                                 float* __restrict__ outq,
                                                 float* __restrict__ out_idx_f) {
    __shared__ int   cd_k[4][128];
    __shared__ float cd_d[4][128];
    __shared__ float rd[4], rs[4];

    const int wid = threadIdx.x >> 6, lane = threadIdx.x & 63;
    const int s = blockIdx.x * 4 + wid;
    const float4 xv = reinterpret_cast<const float4*>(x)[(size_t)s * 64 + lane];

    // exact ||x_s||^2 (all lanes)
    float x2s = xv.x * xv.x + xv.y * xv.y + xv.z * xv.z + xv.w * xv.w;
    #pragma unroll
    for (int off = 32; off; off >>= 1) x2s += __shfl_xor(x2s, off);

    // parallel min over the 16 half-block summaries
    float gm = summ[(size_t)s * 16 + (lane & 15)].x;
    #pragma unroll
    for (int off = 1; off < 16; off <<= 1) gm = fminf(gm, __shfl_xor(gm, off));
    const float lim = gm + TAU;

    float m = 3.4e38f, S1 = 0.f, S2 = 0.f;
    int bk = 0, cnt = 0;
    for (int hb = 0; hb < 16; ++hb) {
        float4 sm = summ[(size_t)s * 16 + hb];
        if (sm.x > lim) continue;
        u64 mk = ((u64)__float_as_uint(sm.w) << 32) | __float_as_uint(sm.z);
        while (mk) {
            int b = __ffsll(mk) - 1; mk &= mk - 1;
            int k = hb * 64 + b;
            float4 cv = reinterpret_cast<const float4*>(cb)[(size_t)k * 64 + lane];
            float r = xv.x * cv.x + xv.y * cv.y + xv.z * cv.z + xv.w * cv.w;
            #pragma unroll
            for (int off = 32; off; off >>= 1) r += __shfl_xor(r, off);
            float dk = (x2s - 2.0f * r) + c2[k];
            if (lane == 0 && cnt < 128) { cd_k[wid][cnt] = k; cd_d[wid][cnt] = dk; }
            ++cnt;
            if (S1 == 0.f)    { m = dk; S1 = 1.f; S2 = 0.f; bk = k; }
            else if (dk < m)  { float f = __expf((dk - m) * INV_T);
                                S2 = f * (S2 + (m - dk) * S1);
                                S1 = S1 * f + 1.f; m = dk; bk = k; }
            else              { float e = __expf((m - dk) * INV_T);
                                S1 += e; S2 += e * (dk - m); }
        }
    }
    float sent = S2 * INV_T / S1 + logf(S1);
    if (lane == 0) { rd[wid] = m; rs[wid] = sent; }
    __syncthreads();

    // lane-parallel histogram update
    if (cnt > 128) cnt = 128;
    for (int c = lane; c < cnt; c += 64) {
        float dk = cd_d[wid][c]; int k = cd_k[wid][c];
        atomicAdd(&hist[k], __expf((m - dk) * INV_T) / S1);
    }

    // fused gather: quantized row = codebook[bk]
    reinterpret_cast<float4*>(outq)[(size_t)s * 64 + lane] =
        reinterpret_cast<const float4*>(cb)[(size_t)bk * 64 + lane];
    if (lane == 0) out_idx_f[s] = (float)bk;

    if (threadIdx.x == 0) {
        pd[blockIdx.x] = rd[0] + rd[1] + rd[2] + rd[3];
        ps[blockIdx.x] = rs[0] + rs[1] + rs[2] + rs[3];
    }
}

// -------------------------------------------------------------- finalize ----
__global__ __launch_bounds__(256) void vq_finalize(const float* __restrict__ hist,
                                                   const float* __restrict__ pd,
                                                   const float* __restrict__ ps,
                                                   float* __restrict__ loss_out) {
    float ae = 0.f, sd = 0.f, se = 0.f;
    for (int k = threadIdx.x; k < KC; k += 256) {
        float p = hist[k] * (1.0f / (float)NS);
        ae += -p * logf(p + 1e-5f);
    }
    for (int b = threadIdx.x; b < 8192; b += 256) { sd += pd[b]; se += ps[b]; }
    #pragma unroll
    for (int off = 32; off; off >>= 1) {
        ae += __shfl_xor(ae, off); sd += __shfl_xor(sd, off); se += __shfl_xor(se, off);
    }
    __shared__ float r[3][4];
    int wid = threadIdx.x >> 6, lane = threadIdx.x & 63;
    if (lane == 0) { r[0][wid] = ae; r[1][wid] = sd; r[2][wid] = se; }
    __syncthreads();
    if (threadIdx.x == 0) {
        float AE = r[0][0] + r[0][1] + r[0][2] + r[0][3];
        float SD = r[1][0] + r[1][1] + r[1][2] + r[1][3];
        float SE = r[2][0] + r[2][1] + r[2][2] + r[2][3];
        float latent = 1.25f * SD / 8388608.0f;
        loss_out[0] = latent + 0.1f * (SE * (1.0f / (float)NS) - AE);
    }
}

extern "C" void kernel_launch(void* const* d_in, const int* in_sizes, int n_in,
                              void* d_out, int out_size, void* d_ws, size_t ws_size,
                              hipStream_t stream) {
    const float* x  = (const float*)d_in[0];
    const float* cb = (const float*)d_in[1];
    float* out = (float*)d_out;
    float* ws  = (float*)d_ws;

    // tiled bf16 codebook in first 512 KB of d_out (overwritten by refine later)
    u16* ct = (u16*)d_out;

    hipMemsetAsync(ws + HIST_OFF, 0, KC * sizeof(float), stream);

    vq_cbprep<<<64, 256, 0, stream>>>(cb, ct, ws + C2_OFF);
    vq_dist<<<512, 256, 0, stream>>>(x, ct, ws + C2_OFF, (float4*)(ws + SUMM_OFF));
    vq_refine<<<NS / 4, 256, 0, stream>>>(x, cb, ws + C2_OFF,
                                          (const float4*)(ws + SUMM_OFF),
                                          ws + HIST_OFF, ws + PD_OFF, ws + PS_OFF,
                                          out, out + 8388609);
    vq_finalize<<<1, 256, 0, stream>>>(ws + HIST_OFF, ws + PD_OFF, ws + PS_OFF,
                                       out + 8388608);
}

// Round 7
// 102.624 us; speedup vs baseline: 1.2757x; 1.0401x over previous
//
#include <hip/hip_runtime.h>
#include <math.h>

typedef unsigned short u16;
typedef unsigned long long u64;
typedef float    f32x4  __attribute__((ext_vector_type(4)));
typedef __bf16   bf16x8 __attribute__((ext_vector_type(8)));

#define NS    32768
#define KC    1024
#define INV_T 100.0f
#define TAU   2.0f

// ws layout (float offsets)
#define C2_OFF   0
#define SUMM_OFF 1024                      // [n][16 halfblocks] float4
#define SUMM_SZ  (NS * 16 * 4)
#define HIST_OFF (SUMM_OFF + SUMM_SZ)
#define PD_OFF   (HIST_OFF + KC)
#define PS_OFF   (PD_OFF + 8192)

// ct: tiled bf16 codebook, 16 tiles (64 codes) x 2048 chunks x 16B = 512 KB
// (lives in d_out, overwritten by refine's quantized output afterwards).
// chunk c within tile = ks*256 + sub*64 + row  (sub = k-octet, row = code 0..63)
#define TILE_U16 16384

__device__ __forceinline__ void gload_lds16(const void* g, void* l) {
    __builtin_amdgcn_global_load_lds((const __attribute__((address_space(1))) void*)g,
                                     (__attribute__((address_space(3))) void*)l, 16, 0, 0);
}

// --------------- cb prep: exact c2 + tiled bf16 codebook (64 blocks) ----
__global__ __launch_bounds__(256) void vq_cbprep(const float* __restrict__ cb,
                                                 u16* __restrict__ ct,
                                                 float* __restrict__ c2) {
    const int b = blockIdx.x;        // 64 blocks: tile T = b>>2, part p = b&3
    const int T = b >> 2, p = b & 3;
    const int t = threadIdx.x, w = t >> 6, lane = t & 63;

    // c2 for 16 rows (exact fp32)
    #pragma unroll
    for (int i = 0; i < 4; ++i) {
        int g = T * 64 + p * 16 + i * 4 + w;
        float4 v = reinterpret_cast<const float4*>(cb)[(size_t)g * 64 + lane];
        float s = v.x * v.x + v.y * v.y + v.z * v.z + v.w * v.w;
        #pragma unroll
        for (int off = 32; off; off >>= 1) s += __shfl_xor(s, off);
        if (lane == 0) c2[g] = s;
    }

    // tiled bf16: this block covers chunks [p*512, p*512+512) of tile T
    #pragma unroll
    for (int i = 0; i < 2; ++i) {
        int c = p * 512 + i * 256 + t;
        int ks = c >> 8, sub = (c >> 6) & 3, row = c & 63;
        const float* src = cb + (size_t)(T * 64 + row) * 256 + ks * 32 + sub * 8;
        float4 a0 = *reinterpret_cast<const float4*>(src);
        float4 a1 = *reinterpret_cast<const float4*>(src + 4);
        bf16x8 v;
        v[0]=(__bf16)a0.x; v[1]=(__bf16)a0.y; v[2]=(__bf16)a0.z; v[3]=(__bf16)a0.w;
        v[4]=(__bf16)a1.x; v[5]=(__bf16)a1.y; v[6]=(__bf16)a1.z; v[7]=(__bf16)a1.w;
        *reinterpret_cast<bf16x8*>(ct + (size_t)T * TILE_U16 + (size_t)c * 8) = v;
    }
}

// ---- distance MFMA: A persistent in registers (32 samples/wave -> no spill),
//      B dbuf-streamed via LDS. grid 1024 = 256 sample-groups (128 samples)
//      x 4 code-quarters (256 codes). 4 waves; wave = 32 samples, af[2][8]=64 VGPR.
__global__ __launch_bounds__(256, 2) void vq_dist(const float* __restrict__ x,
                                                  const u16* __restrict__ ct,
                                                  const float* __restrict__ c2,
                                                  float4* __restrict__ summ) {
    __shared__ __align__(16) u16 Bs[2][TILE_U16];   // 2 x 32 KB

    // XCD swizzle: each XCD owns 32 sample-groups x 4 code-quarters
    const int id = blockIdx.x;
    const int xcd = id & 7, r0 = id >> 3;          // r0 0..127
    const int sq = xcd * 32 + (r0 >> 2);           // 0..255
    const int cq = r0 & 3;                         // 0..3
    const int sBase = sq * 128;
    const int tile0 = cq * 4;

    const int t = threadIdx.x, w = t >> 6, lane = t & 63;
    const int lo16 = lane & 15, hi = lane >> 4;

    #define STAGE(buf, tile)                                                      \
        do {                                                                      \
            const u16* bT_ = ct + (size_t)(tile) * TILE_U16;                      \
            _Pragma("unroll")                                                     \
            for (int i_ = 0; i_ < 8; ++i_) {                                      \
                int c0_ = w * 512 + i_ * 64;                                      \
                gload_lds16(bT_ + (size_t)(c0_ + lane) * 8, &Bs[buf][c0_ * 8]);   \
            }                                                                     \
        } while (0)

    STAGE(0, tile0);

    // Load this wave's entire A-operand (32 samples x 256 k) into 64 VGPRs.
    const float* aw = x + (size_t)(sBase + w * 32) * 256;
    bf16x8 af[2][8];
    #pragma unroll
    for (int m = 0; m < 2; ++m) {
        #pragma unroll
        for (int ks = 0; ks < 8; ++ks) {
            const float* ap = aw + (size_t)(m * 16 + lo16) * 256 + ks * 32 + hi * 8;
            float4 a0 = *reinterpret_cast<const float4*>(ap);
            float4 a1 = *reinterpret_cast<const float4*>(ap + 4);
            bf16x8 v;
            v[0]=(__bf16)a0.x; v[1]=(__bf16)a0.y; v[2]=(__bf16)a0.z; v[3]=(__bf16)a0.w;
            v[4]=(__bf16)a1.x; v[5]=(__bf16)a1.y; v[6]=(__bf16)a1.z; v[7]=(__bf16)a1.w;
            af[m][ks] = v;
        }
    }
    __syncthreads();

    int cur = 0;
    for (int tt = 0; tt < 4; ++tt) {
        if (tt < 3) STAGE(cur ^ 1, tile0 + tt + 1);   // overlaps with MFMAs below

        const u16* bsc = &Bs[cur][0];
        f32x4 acc[2][4];
        #pragma unroll
        for (int m = 0; m < 2; ++m)
            #pragma unroll
            for (int n = 0; n < 4; ++n) acc[m][n] = (f32x4)0.f;

        #pragma unroll
        for (int ks = 0; ks < 8; ++ks) {
            bf16x8 bfr[4];
            #pragma unroll
            for (int n = 0; n < 4; ++n)
                bfr[n] = *reinterpret_cast<const bf16x8*>(
                    &bsc[((size_t)ks * 256 + hi * 64 + n * 16 + lo16) * 8]);
            #pragma unroll
            for (int m = 0; m < 2; ++m)
                #pragma unroll
                for (int n = 0; n < 4; ++n)
                    acc[m][n] = __builtin_amdgcn_mfma_f32_16x16x32_bf16(af[m][ks], bfr[n], acc[m][n], 0, 0, 0);
        }

        // Epilogue for this 64-code tile: dd = c2 - 2*acc (x^2 cancels)
        const int cBase = (tile0 + tt) * 64;
        float c2v[4];
        #pragma unroll
        for (int j = 0; j < 4; ++j) c2v[j] = c2[cBase + j * 16 + lo16];

        #pragma unroll
        for (int m = 0; m < 2; ++m) {
            #pragma unroll
            for (int r = 0; r < 4; ++r) {
                const int R = sBase + w * 32 + m * 16 + hi * 4 + r;
                float dd[4];
                #pragma unroll
                for (int j = 0; j < 4; ++j) dd[j] = fmaf(-2.0f, acc[m][j][r], c2v[j]);
                float bm = fminf(fminf(dd[0], dd[1]), fminf(dd[2], dd[3]));
                #pragma unroll
                for (int off = 1; off < 16; off <<= 1) bm = fminf(bm, __shfl_xor(bm, off));
                const float thr = bm + TAU;
                u64 mk = 0ull;
                #pragma unroll
                for (int n = 0; n < 4; ++n) {
                    u64 b = __ballot(dd[n] < thr);
                    mk |= ((b >> (hi * 16)) & 0xFFFFull) << (n * 16);
                }
                if (lo16 == 0) {
                    float4 o;
                    o.x = bm;
                    o.y = 0.f;
                    o.z = __uint_as_float((unsigned)(mk & 0xFFFFFFFFull));
                    o.w = __uint_as_float((unsigned)(mk >> 32));
                    summ[(size_t)R * 16 + tile0 + tt] = o;
                }
            }
        }
        __syncthreads();     // stage(next) complete; buffer swap safe
        cur ^= 1;
    }
    #undef STAGE
}

// ---------- exact fp32 refine, single-pass, fused gather + histogram ----
__global__ __launch_bounds__(256) void vq_refine(const float* __restrict__ x,
                                                 const float* __restrict__ cb,
                                                 const float* __restrict__ c2,
                                                 const float4* __restrict__ summ,
                                                 float* __restrict__ hist,
                                                 float* __restrict__ pd,
                                                 float* __restrict__ ps,
                                                 float* __restrict__ outq,
                                                 float* __restrict__ out_idx_f) {
    __shared__ int   cd_k[4][128];
    __shared__ float cd_d[4][128];
    __shared__ float rd[4], rs[4];

    const int wid = threadIdx.x >> 6, lane = threadIdx.x & 63;
    const int s = blockIdx.x * 4 + wid;
    const float4 xv = reinterpret_cast<const float4*>(x)[(size_t)s * 64 + lane];

    // exact ||x_s||^2 (all lanes)
    float x2s = xv.x * xv.x + xv.y * xv.y + xv.z * xv.z + xv.w * xv.w;
    #pragma unroll
    for (int off = 32; off; off >>= 1) x2s += __shfl_xor(x2s, off);

    // parallel min over the 16 half-block summaries
    float gm = summ[(size_t)s * 16 + (lane & 15)].x;
    #pragma unroll
    for (int off = 1; off < 16; off <<= 1) gm = fminf(gm, __shfl_xor(gm, off));
    const float lim = gm + TAU;

    float m = 3.4e38f, S1 = 0.f, S2 = 0.f;
    int bk = 0, cnt = 0;
    for (int hb = 0; hb < 16; ++hb) {
        float4 sm = summ[(size_t)s * 16 + hb];
        if (sm.x > lim) continue;
        u64 mk = ((u64)__float_as_uint(sm.w) << 32) | __float_as_uint(sm.z);
        while (mk) {
            int b = __ffsll(mk) - 1; mk &= mk - 1;
            int k = hb * 64 + b;
            float4 cv = reinterpret_cast<const float4*>(cb)[(size_t)k * 64 + lane];
            float r = xv.x * cv.x + xv.y * cv.y + xv.z * cv.z + xv.w * cv.w;
            #pragma unroll
            for (int off = 32; off; off >>= 1) r += __shfl_xor(r, off);
            float dk = (x2s - 2.0f * r) + c2[k];
            if (lane == 0 && cnt < 128) { cd_k[wid][cnt] = k; cd_d[wid][cnt] = dk; }
            ++cnt;
            if (S1 == 0.f)    { m = dk; S1 = 1.f; S2 = 0.f; bk = k; }
            else if (dk < m)  { float f = __expf((dk - m) * INV_T);
                                S2 = f * (S2 + (m - dk) * S1);
                                S1 = S1 * f + 1.f; m = dk; bk = k; }
            else              { float e = __expf((m - dk) * INV_T);
                                S1 += e; S2 += e * (dk - m); }
        }
    }
    float sent = S2 * INV_T / S1 + logf(S1);
    if (lane == 0) { rd[wid] = m; rs[wid] = sent; }
    __syncthreads();

    // lane-parallel histogram update
    if (cnt > 128) cnt = 128;
    for (int c = lane; c < cnt; c += 64) {
        float dk = cd_d[wid][c]; int k = cd_k[wid][c];
        atomicAdd(&hist[k], __expf((m - dk) * INV_T) / S1);
    }

    // fused gather: quantized row = codebook[bk]
    reinterpret_cast<float4*>(outq)[(size_t)s * 64 + lane] =
        reinterpret_cast<const float4*>(cb)[(size_t)bk * 64 + lane];
    if (lane == 0) out_idx_f[s] = (float)bk;

    if (threadIdx.x == 0) {
        pd[blockIdx.x] = rd[0] + rd[1] + rd[2] + rd[3];
        ps[blockIdx.x] = rs[0] + rs[1] + rs[2] + rs[3];
    }
}

// -------------------------------------------------------------- finalize ----
__global__ __launch_bounds__(256) void vq_finalize(const float* __restrict__ hist,
                                                   const float* __restrict__ pd,
                                                   const float* __restrict__ ps,
                                                   float* __restrict__ loss_out) {
    float ae = 0.f, sd = 0.f, se = 0.f;
    for (int k = threadIdx.x; k < KC; k += 256) {
        float p = hist[k] * (1.0f / (float)NS);
        ae += -p * logf(p + 1e-5f);
    }
    for (int b = threadIdx.x; b < 8192; b += 256) { sd += pd[b]; se += ps[b]; }
    #pragma unroll
    for (int off = 32; off; off >>= 1) {
        ae += __shfl_xor(ae, off); sd += __shfl_xor(sd, off); se += __shfl_xor(se, off);
    }
    __shared__ float r[3][4];
    int wid = threadIdx.x >> 6, lane = threadIdx.x & 63;
    if (lane == 0) { r[0][wid] = ae; r[1][wid] = sd; r[2][wid] = se; }
    __syncthreads();
    if (threadIdx.x == 0) {
        float AE = r[0][0] + r[0][1] + r[0][2] + r[0][3];
        float SD = r[1][0] + r[1][1] + r[1][2] + r[1][3];
        float SE = r[2][0] + r[2][1] + r[2][2] + r[2][3];
        float latent = 1.25f * SD / 8388608.0f;
        loss_out[0] = latent + 0.1f * (SE * (1.0f / (float)NS) - AE);
    }
}

extern "C" void kernel_launch(void* const* d_in, const int* in_sizes, int n_in,
                              void* d_out, int out_size, void* d_ws, size_t ws_size,
                              hipStream_t stream) {
    const float* x  = (const float*)d_in[0];
    const float* cb = (const float*)d_in[1];
    float* out = (float*)d_out;
    float* ws  = (float*)d_ws;

    // tiled bf16 codebook in first 512 KB of d_out (overwritten by refine later)
    u16* ct = (u16*)d_out;

    hipMemsetAsync(ws + HIST_OFF, 0, KC * sizeof(float), stream);

    vq_cbprep<<<64, 256, 0, stream>>>(cb, ct, ws + C2_OFF);
    vq_dist<<<1024, 256, 0, stream>>>(x, ct, ws + C2_OFF, (float4*)(ws + SUMM_OFF));
    vq_refine<<<NS / 4, 256, 0, stream>>>(x, cb, ws + C2_OFF,
                                          (const float4*)(ws + SUMM_OFF),
                                          ws + HIST_OFF, ws + PD_OFF, ws + PS_OFF,
                                          out, out + 8388609);
    vq_finalize<<<1, 256, 0, stream>>>(ws + HIST_OFF, ws + PD_OFF, ws + PS_OFF,
                                       out + 8388608);
}